// Round 3
// baseline (1060.576 us; speedup 1.0000x reference)
//
#include <hip/hip_runtime.h>
#include <hip/hip_bf16.h>

typedef unsigned short u16;
typedef unsigned int u32;
typedef __attribute__((ext_vector_type(4))) float f32x4;
typedef __attribute__((ext_vector_type(16))) float f32x16;
typedef __attribute__((ext_vector_type(8))) short short8;

#define SEQ 2048
#define FD  1024
#define NH  16
#define DHD 64

__device__ __forceinline__ u16 f2bf(float f) {
  __hip_bfloat16 h = __float2bfloat16(f);
  return *reinterpret_cast<u16*>(&h);
}
__device__ __forceinline__ u32 pack2bf(float lo, float hi) {
  return (u32)f2bf(lo) | ((u32)f2bf(hi) << 16);
}

// ---- shared GEMM body: 128x128 tile of C = A[M,K] * B[N,K]^T (K-major both),
// bf16 MFMA 16x16x32, fp32 accum. A/B staged (with fp32->bf16 cvt if needed).
template <typename TA, typename TB>
__device__ __forceinline__ void gemm_bt_body(const TA* __restrict__ A, const TB* __restrict__ Bm,
                                             int m0, int n0, u16* As, u16* Bs, f32x4 acc[4][4]) {
  const int tid = threadIdx.x;
  const int lane = tid & 63;
  const int wr = (tid >> 7) & 1;   // wave row quadrant
  const int wc = (tid >> 6) & 1;   // wave col quadrant
  const int lr = lane & 15;
  const int lk = (lane >> 4) << 3;
#pragma unroll
  for (int m = 0; m < 4; ++m)
#pragma unroll
    for (int n = 0; n < 4; ++n) acc[m][n] = {0.f, 0.f, 0.f, 0.f};

  const int r_ = tid >> 2;
  const int c_ = (tid & 3) << 3;

  for (int k0 = 0; k0 < FD; k0 += 32) {
    __syncthreads();
#pragma unroll
    for (int c = 0; c < 2; ++c) {   // stage A tile half (64 rows x 32 cols)
      int r = c * 64 + r_;
      const TA* s = A + (size_t)(m0 + r) * FD + k0 + c_;
      short8 o;
      if constexpr (sizeof(TA) == 4) {
        f32x4 v0 = *reinterpret_cast<const f32x4*>(s);
        f32x4 v1 = *reinterpret_cast<const f32x4*>(s + 4);
#pragma unroll
        for (int j = 0; j < 4; ++j) { o[j] = (short)f2bf(v0[j]); o[4 + j] = (short)f2bf(v1[j]); }
      } else {
        o = *reinterpret_cast<const short8*>(s);
      }
      *reinterpret_cast<short8*>(&As[r * 32 + c_]) = o;
    }
#pragma unroll
    for (int c = 0; c < 2; ++c) {   // stage B tile half
      int r = c * 64 + r_;
      const TB* s = Bm + (size_t)(n0 + r) * FD + k0 + c_;
      short8 o;
      if constexpr (sizeof(TB) == 4) {
        f32x4 v0 = *reinterpret_cast<const f32x4*>(s);
        f32x4 v1 = *reinterpret_cast<const f32x4*>(s + 4);
#pragma unroll
        for (int j = 0; j < 4; ++j) { o[j] = (short)f2bf(v0[j]); o[4 + j] = (short)f2bf(v1[j]); }
      } else {
        o = *reinterpret_cast<const short8*>(s);
      }
      *reinterpret_cast<short8*>(&Bs[r * 32 + c_]) = o;
    }
    __syncthreads();

    short8 a[4], b[4];
#pragma unroll
    for (int m = 0; m < 4; ++m)
      a[m] = *reinterpret_cast<const short8*>(&As[(wr * 64 + m * 16 + lr) * 32 + lk]);
#pragma unroll
    for (int n = 0; n < 4; ++n)
      b[n] = *reinterpret_cast<const short8*>(&Bs[(wc * 64 + n * 16 + lr) * 32 + lk]);
#pragma unroll
    for (int m = 0; m < 4; ++m)
#pragma unroll
      for (int n = 0; n < 4; ++n)
        acc[m][n] = __builtin_amdgcn_mfma_f32_16x16x32_bf16(a[m], b[n], acc[m][n], 0, 0, 0);
  }
}

// ---- fused QKV projection: z selects which of Q/K/V. q,k -> [B,H,S,DH] bf16; v -> [B,H,DH,S] bf16
// q is pre-scaled by (1/sqrt(DH))*log2(e) so attention works in exp2 domain.
__global__ __launch_bounds__(256) void proj_qkv_kernel(
    const float* __restrict__ Q, const float* __restrict__ K, const float* __restrict__ V,
    const float* __restrict__ Wq, const float* __restrict__ Wk, const float* __restrict__ Wv,
    const float* __restrict__ bq, const float* __restrict__ bk, const float* __restrict__ bv,
    u16* __restrict__ qh, u16* __restrict__ kh, u16* __restrict__ vT) {
  __shared__ u16 As[128 * 32];
  __shared__ u16 Bs[128 * 32];
  const int which = blockIdx.z;
  const float* A    = (which == 0) ? Q  : (which == 1) ? K  : V;
  const float* W    = (which == 0) ? Wq : (which == 1) ? Wk : Wv;
  const float* bias = (which == 0) ? bq : (which == 1) ? bk : bv;
  u16* out          = (which == 0) ? qh : (which == 1) ? kh : vT;
  const int m0 = blockIdx.y * 128, n0 = blockIdx.x * 128;
  const float qscale = 0.18033688011112042f;  // (1/8) * log2(e)

  f32x4 acc[4][4];
  gemm_bt_body(A, W, m0, n0, As, Bs, acc);

  const int lane = threadIdx.x & 63;
  const int wr = (threadIdx.x >> 7) & 1, wc = (threadIdx.x >> 6) & 1;
  const int rbase = m0 + wr * 64 + ((lane >> 4) << 2);
  const int cbase = n0 + wc * 64 + (lane & 15);
#pragma unroll
  for (int n = 0; n < 4; ++n) {
    const int col = cbase + n * 16;
    const float bvv = bias[col];
    const int h = col >> 6, dh = col & 63;
#pragma unroll
    for (int m = 0; m < 4; ++m) {
#pragma unroll
      for (int r = 0; r < 4; ++r) {
        const int row = rbase + m * 16 + r;
        const int b = row >> 11, s = row & 2047;
        float v = acc[m][n][r] + bvv;
        if (which == 0) v *= qscale;
        size_t idx;
        if (which < 2) idx = ((size_t)((b * 16 + h) * 2048 + s)) * 64 + dh;   // [B,H,S,DH]
        else           idx = ((size_t)((b * 16 + h) * 64 + dh)) * 2048 + s;   // [B,H,DH,S]
        out[idx] = f2bf(v);
      }
    }
  }
}

// ---- flash attention, swapped-operand 32x32 structure, 4-way KV split per block:
// each block owns ONE 32-row q-group; wave w processes kv in [w*512, w*512+512);
// partials (m, l, O) combined through LDS at the end. Main loop unchanged from R2.
__global__ __launch_bounds__(256, 8) void attn_kernel(
    const u16* __restrict__ qh, const u16* __restrict__ kh, const u16* __restrict__ vT,
    const float* __restrict__ mask, u16* __restrict__ O) {
  __shared__ float mred[4][32];
  __shared__ float lred[4][32];
  __shared__ float O_l[32][65];   // stride 65 -> bank = (q + d) & 31, worst 2-way (free)
  const int wave = threadIdx.x >> 6, lane = threadIdx.x & 63;
  const int bh = blockIdx.x >> 6;
  const int q0 = (blockIdx.x & 63) * 32;
  const int lq = lane & 31;
  const int hi = lane >> 5;
  const u16* qp = qh + (size_t)bh * SEQ * DHD;
  const u16* kp = kh + (size_t)bh * SEQ * DHD;
  const u16* vp = vT + (size_t)bh * DHD * SEQ;
  const float* mrow = mask + (size_t)(q0 + lq) * SEQ;
  const float L2E = 1.44269504088896340736f;

  short8 qf[4];
#pragma unroll
  for (int d = 0; d < 4; ++d)
    qf[d] = *reinterpret_cast<const short8*>(&qp[(size_t)(q0 + lq) * DHD + d * 16 + hi * 8]);

  f32x16 oacc[2];
#pragma unroll
  for (int e = 0; e < 16; ++e) { oacc[0][e] = 0.f; oacc[1][e] = 0.f; }
  float m2 = -INFINITY, lsum = 0.f;

  const int kv_begin = wave * (SEQ / 4);
  const int kv_end = kv_begin + (SEQ / 4);
  for (int kv0 = kv_begin; kv0 < kv_end; kv0 += 64) {
    // S^T[kv][q] accumulated over d; lane holds col q=lq, rows kv=(e&3)+8*(e>>2)+4*hi (+32*h2)
    f32x16 st[2];
#pragma unroll
    for (int h2 = 0; h2 < 2; ++h2) {
      f32x16 z;
#pragma unroll
      for (int e = 0; e < 16; ++e) z[e] = 0.f;
#pragma unroll
      for (int d = 0; d < 4; ++d) {
        short8 ak = *reinterpret_cast<const short8*>(
            &kp[(size_t)(kv0 + h2 * 32 + lq) * DHD + d * 16 + hi * 8]);
        z = __builtin_amdgcn_mfma_f32_32x32x16_bf16(ak, qf[d], z, 0, 0, 0);
      }
      st[h2] = z;
    }
    // mask add (exp2 domain): p = s + mask*log2e
    float p[32];
#pragma unroll
    for (int h2 = 0; h2 < 2; ++h2)
#pragma unroll
      for (int g = 0; g < 4; ++g) {
        f32x4 mv = *reinterpret_cast<const f32x4*>(&mrow[kv0 + h2 * 32 + g * 8 + hi * 4]);
#pragma unroll
        for (int j = 0; j < 4; ++j)
          p[h2 * 16 + g * 4 + j] = fmaf(mv[j], L2E, st[h2][g * 4 + j]);
      }
    // row max: in-register tree + one cross-half exchange
    float t8[8];
#pragma unroll
    for (int i = 0; i < 8; ++i)
      t8[i] = fmaxf(fmaxf(p[i], p[i + 8]), fmaxf(p[i + 16], p[i + 24]));
#pragma unroll
    for (int i = 0; i < 4; ++i) t8[i] = fmaxf(t8[i], t8[i + 4]);
    float mt = fmaxf(fmaxf(t8[0], t8[1]), fmaxf(t8[2], t8[3]));
    mt = fmaxf(mt, __shfl_xor(mt, 32));
    const float mnew = fmaxf(m2, mt);
    const float alpha = __builtin_amdgcn_exp2f(m2 - mnew);
    m2 = mnew;
#pragma unroll
    for (int i = 0; i < 32; ++i) p[i] = __builtin_amdgcn_exp2f(p[i] - m2);
    float s8[8];
#pragma unroll
    for (int i = 0; i < 8; ++i) s8[i] = (p[i] + p[i + 8]) + (p[i + 16] + p[i + 24]);
#pragma unroll
    for (int i = 0; i < 4; ++i) s8[i] += s8[i + 4];
    float ssum = (s8[0] + s8[1]) + (s8[2] + s8[3]);
    ssum += __shfl_xor(ssum, 32);
    lsum = lsum * alpha + ssum;
#pragma unroll
    for (int e = 0; e < 16; ++e) { oacc[0][e] *= alpha; oacc[1][e] *= alpha; }

    // P^T fragments (B-operand) via pack + permlane32_swap; O^T += V^T . P^T
#pragma unroll
    for (int kb = 0; kb < 4; ++kb) {
      const int pb = (kb >> 1) * 16 + (kb & 1) * 8;
      u32 x = pack2bf(p[pb + 0], p[pb + 1]);
      u32 y = pack2bf(p[pb + 4], p[pb + 5]);
      asm volatile("v_permlane32_swap_b32 %0, %1" : "+v"(x), "+v"(y));
      u32 zz = pack2bf(p[pb + 2], p[pb + 3]);
      u32 w = pack2bf(p[pb + 6], p[pb + 7]);
      asm volatile("v_permlane32_swap_b32 %0, %1" : "+v"(zz), "+v"(w));
      union { u32 u[4]; short8 s; } bf;
      bf.u[0] = x; bf.u[1] = zz; bf.u[2] = y; bf.u[3] = w;
#pragma unroll
      for (int db = 0; db < 2; ++db) {
        short8 av = *reinterpret_cast<const short8*>(
            &vp[(size_t)(db * 32 + lq) * SEQ + kv0 + kb * 16 + hi * 8]);
        oacc[db] = __builtin_amdgcn_mfma_f32_32x32x16_bf16(av, bf.s, oacc[db], 0, 0, 0);
      }
    }
  }

  // ---- cross-wave combine of (m, l, O) partials ----
  if (hi == 0) mred[wave][lq] = m2;
  __syncthreads();
  const float M = fmaxf(fmaxf(mred[0][lq], mred[1][lq]), fmaxf(mred[2][lq], mred[3][lq]));
  const float beta = __builtin_amdgcn_exp2f(m2 - M);
#pragma unroll
  for (int e = 0; e < 16; ++e) { oacc[0][e] *= beta; oacc[1][e] *= beta; }
  if (hi == 0) lred[wave][lq] = lsum * beta;

#pragma unroll
  for (int w = 0; w < 4; ++w) {
    if (wave == w) {
#pragma unroll
      for (int db = 0; db < 2; ++db)
#pragma unroll
        for (int e = 0; e < 16; ++e) {
          const int d = db * 32 + (e & 3) + 8 * (e >> 2) + 4 * hi;
          if (w == 0) O_l[lq][d] = oacc[db][e];
          else        O_l[lq][d] += oacc[db][e];
        }
    }
    __syncthreads();
  }

  // ---- store: O in [B,S,H,DH] bf16; each thread handles 8 consecutive d of one q-row
  const int b = bh >> 4, h = bh & 15;
  const int q = threadIdx.x >> 3;
  const int d0 = (threadIdx.x & 7) * 8;
  const float linv = 1.0f / (lred[0][q] + lred[1][q] + lred[2][q] + lred[3][q]);
  union { u16 u[8]; short8 s; } pk;
#pragma unroll
  for (int j = 0; j < 8; ++j) pk.u[j] = f2bf(O_l[q][d0 + j] * linv);
  *reinterpret_cast<short8*>(&O[((size_t)(b * SEQ + q0 + q) * NH + h) * DHD + d0]) = pk.s;
}

// ---- output projection: d_out = O @ Wo^T + bo (fp32 out)
__global__ __launch_bounds__(256) void out_proj_kernel(
    const u16* __restrict__ O, const float* __restrict__ Wo, const float* __restrict__ bo,
    float* __restrict__ out) {
  __shared__ u16 As[128 * 32];
  __shared__ u16 Bs[128 * 32];
  const int m0 = blockIdx.y * 128, n0 = blockIdx.x * 128;
  f32x4 acc[4][4];
  gemm_bt_body(O, Wo, m0, n0, As, Bs, acc);

  const int lane = threadIdx.x & 63;
  const int wr = (threadIdx.x >> 7) & 1, wc = (threadIdx.x >> 6) & 1;
  const int rbase = m0 + wr * 64 + ((lane >> 4) << 2);
  const int cbase = n0 + wc * 64 + (lane & 15);
#pragma unroll
  for (int n = 0; n < 4; ++n) {
    const int col = cbase + n * 16;
    const float bvv = bo[col];
#pragma unroll
    for (int m = 0; m < 4; ++m)
#pragma unroll
      for (int r = 0; r < 4; ++r) {
        const int row = rbase + m * 16 + r;
        out[(size_t)row * FD + col] = acc[m][n][r] + bvv;
      }
  }
}

extern "C" void kernel_launch(void* const* d_in, const int* in_sizes, int n_in,
                              void* d_out, int out_size, void* d_ws, size_t ws_size,
                              hipStream_t stream) {
  (void)in_sizes; (void)n_in; (void)out_size; (void)ws_size;
  const float* Q    = (const float*)d_in[0];
  const float* K    = (const float*)d_in[1];
  const float* V    = (const float*)d_in[2];
  const float* mask = (const float*)d_in[3];
  const float* Wq   = (const float*)d_in[4];
  const float* bq   = (const float*)d_in[5];
  const float* Wk   = (const float*)d_in[6];
  const float* bk   = (const float*)d_in[7];
  const float* Wv   = (const float*)d_in[8];
  const float* bv   = (const float*)d_in[9];
  const float* Wo   = (const float*)d_in[10];
  const float* bo   = (const float*)d_in[11];
  float* out = (float*)d_out;

  u16* ws = (u16*)d_ws;
  const size_t SZ = (size_t)4096 * 1024;   // B*S*F elements
  u16* qh = ws;            // [B,H,S,DH] bf16 (pre-scaled by 0.125*log2e)
  u16* kh = qh + SZ;       // [B,H,S,DH] bf16
  u16* vT = kh + SZ;       // [B,H,DH,S] bf16
  u16* O  = vT + SZ;       // [B,S,H,DH] bf16

  dim3 gproj(FD / 128, (2 * SEQ) / 128, 3);      // (8, 32, 3)
  proj_qkv_kernel<<<gproj, 256, 0, stream>>>(Q, K, V, Wq, Wk, Wv, bq, bk, bv, qh, kh, vT);

  attn_kernel<<<dim3(2048), 256, 0, stream>>>(qh, kh, vT, mask, O);

  out_proj_kernel<<<dim3(FD / 128, (2 * SEQ) / 128), 256, 0, stream>>>(O, Wo, bo, out);
}

// Round 4
// 298.165 us; speedup vs baseline: 3.5570x; 3.5570x over previous
//
#include <hip/hip_runtime.h>
#include <hip/hip_bf16.h>

typedef unsigned short u16;
typedef unsigned int u32;
typedef __attribute__((ext_vector_type(4))) float f32x4;
typedef __attribute__((ext_vector_type(16))) float f32x16;
typedef __attribute__((ext_vector_type(8))) short short8;

#define SEQ 2048
#define FD  1024
#define NH  16
#define DHD 64

__device__ __forceinline__ u16 f2bf(float f) {
  __hip_bfloat16 h = __float2bfloat16(f);
  return *reinterpret_cast<u16*>(&h);
}
__device__ __forceinline__ u32 pack2bf(float lo, float hi) {
  return (u32)f2bf(lo) | ((u32)f2bf(hi) << 16);
}

// ---- shared GEMM body: 128x128 tile of C = A[M,K] * B[N,K]^T (K-major both),
// bf16 MFMA 16x16x32, fp32 accum. A/B staged (with fp32->bf16 cvt if needed).
template <typename TA, typename TB>
__device__ __forceinline__ void gemm_bt_body(const TA* __restrict__ A, const TB* __restrict__ Bm,
                                             int m0, int n0, u16* As, u16* Bs, f32x4 acc[4][4]) {
  const int tid = threadIdx.x;
  const int lane = tid & 63;
  const int wr = (tid >> 7) & 1;   // wave row quadrant
  const int wc = (tid >> 6) & 1;   // wave col quadrant
  const int lr = lane & 15;
  const int lk = (lane >> 4) << 3;
#pragma unroll
  for (int m = 0; m < 4; ++m)
#pragma unroll
    for (int n = 0; n < 4; ++n) acc[m][n] = {0.f, 0.f, 0.f, 0.f};

  const int r_ = tid >> 2;
  const int c_ = (tid & 3) << 3;

  for (int k0 = 0; k0 < FD; k0 += 32) {
    __syncthreads();
#pragma unroll
    for (int c = 0; c < 2; ++c) {   // stage A tile half (64 rows x 32 cols)
      int r = c * 64 + r_;
      const TA* s = A + (size_t)(m0 + r) * FD + k0 + c_;
      short8 o;
      if constexpr (sizeof(TA) == 4) {
        f32x4 v0 = *reinterpret_cast<const f32x4*>(s);
        f32x4 v1 = *reinterpret_cast<const f32x4*>(s + 4);
#pragma unroll
        for (int j = 0; j < 4; ++j) { o[j] = (short)f2bf(v0[j]); o[4 + j] = (short)f2bf(v1[j]); }
      } else {
        o = *reinterpret_cast<const short8*>(s);
      }
      *reinterpret_cast<short8*>(&As[r * 32 + c_]) = o;
    }
#pragma unroll
    for (int c = 0; c < 2; ++c) {   // stage B tile half
      int r = c * 64 + r_;
      const TB* s = Bm + (size_t)(n0 + r) * FD + k0 + c_;
      short8 o;
      if constexpr (sizeof(TB) == 4) {
        f32x4 v0 = *reinterpret_cast<const f32x4*>(s);
        f32x4 v1 = *reinterpret_cast<const f32x4*>(s + 4);
#pragma unroll
        for (int j = 0; j < 4; ++j) { o[j] = (short)f2bf(v0[j]); o[4 + j] = (short)f2bf(v1[j]); }
      } else {
        o = *reinterpret_cast<const short8*>(s);
      }
      *reinterpret_cast<short8*>(&Bs[r * 32 + c_]) = o;
    }
    __syncthreads();

    short8 a[4], b[4];
#pragma unroll
    for (int m = 0; m < 4; ++m)
      a[m] = *reinterpret_cast<const short8*>(&As[(wr * 64 + m * 16 + lr) * 32 + lk]);
#pragma unroll
    for (int n = 0; n < 4; ++n)
      b[n] = *reinterpret_cast<const short8*>(&Bs[(wc * 64 + n * 16 + lr) * 32 + lk]);
#pragma unroll
    for (int m = 0; m < 4; ++m)
#pragma unroll
      for (int n = 0; n < 4; ++n)
        acc[m][n] = __builtin_amdgcn_mfma_f32_16x16x32_bf16(a[m], b[n], acc[m][n], 0, 0, 0);
  }
}

// ---- fused QKV projection: z selects which of Q/K/V. q,k -> [B,H,S,DH] bf16; v -> [B,H,DH,S] bf16
// q is pre-scaled by (1/sqrt(DH))*log2(e) so attention works in exp2 domain.
__global__ __launch_bounds__(256) void proj_qkv_kernel(
    const float* __restrict__ Q, const float* __restrict__ K, const float* __restrict__ V,
    const float* __restrict__ Wq, const float* __restrict__ Wk, const float* __restrict__ Wv,
    const float* __restrict__ bq, const float* __restrict__ bk, const float* __restrict__ bv,
    u16* __restrict__ qh, u16* __restrict__ kh, u16* __restrict__ vT) {
  __shared__ u16 As[128 * 32];
  __shared__ u16 Bs[128 * 32];
  const int which = blockIdx.z;
  const float* A    = (which == 0) ? Q  : (which == 1) ? K  : V;
  const float* W    = (which == 0) ? Wq : (which == 1) ? Wk : Wv;
  const float* bias = (which == 0) ? bq : (which == 1) ? bk : bv;
  u16* out          = (which == 0) ? qh : (which == 1) ? kh : vT;
  const int m0 = blockIdx.y * 128, n0 = blockIdx.x * 128;
  const float qscale = 0.18033688011112042f;  // (1/8) * log2(e)

  f32x4 acc[4][4];
  gemm_bt_body(A, W, m0, n0, As, Bs, acc);

  const int lane = threadIdx.x & 63;
  const int wr = (threadIdx.x >> 7) & 1, wc = (threadIdx.x >> 6) & 1;
  const int rbase = m0 + wr * 64 + ((lane >> 4) << 2);
  const int cbase = n0 + wc * 64 + (lane & 15);
#pragma unroll
  for (int n = 0; n < 4; ++n) {
    const int col = cbase + n * 16;
    const float bvv = bias[col];
    const int h = col >> 6, dh = col & 63;
#pragma unroll
    for (int m = 0; m < 4; ++m) {
#pragma unroll
      for (int r = 0; r < 4; ++r) {
        const int row = rbase + m * 16 + r;
        const int b = row >> 11, s = row & 2047;
        float v = acc[m][n][r] + bvv;
        if (which == 0) v *= qscale;
        size_t idx;
        if (which < 2) idx = ((size_t)((b * 16 + h) * 2048 + s)) * 64 + dh;   // [B,H,S,DH]
        else           idx = ((size_t)((b * 16 + h) * 64 + dh)) * 2048 + s;   // [B,H,DH,S]
        out[idx] = f2bf(v);
      }
    }
  }
}

// ---- flash attention, swapped-operand 32x32 structure, 4-way KV split per block:
// each block owns ONE 32-row q-group; wave w processes kv in [w*512, w*512+512);
// partials (m, l, O) combined through LDS at the end.
// launch_bounds min-waves=4 (128 VGPR cap): R3's (256,8) forced a 64-VGPR budget
// -> accumulator spill -> 1.5 GB scratch writes. Body naturally fits ~64 VGPR.
__global__ __launch_bounds__(256, 4) void attn_kernel(
    const u16* __restrict__ qh, const u16* __restrict__ kh, const u16* __restrict__ vT,
    const float* __restrict__ mask, u16* __restrict__ O) {
  __shared__ float mred[4][32];
  __shared__ float lred[4][32];
  __shared__ float O_l[32][65];   // stride 65 -> bank = (q + d) & 31, worst 2-way (free)
  const int wave = threadIdx.x >> 6, lane = threadIdx.x & 63;
  const int bh = blockIdx.x >> 6;
  const int q0 = (blockIdx.x & 63) * 32;
  const int lq = lane & 31;
  const int hi = lane >> 5;
  const u16* qp = qh + (size_t)bh * SEQ * DHD;
  const u16* kp = kh + (size_t)bh * SEQ * DHD;
  const u16* vp = vT + (size_t)bh * DHD * SEQ;
  const float* mrow = mask + (size_t)(q0 + lq) * SEQ;
  const float L2E = 1.44269504088896340736f;

  short8 qf[4];
#pragma unroll
  for (int d = 0; d < 4; ++d)
    qf[d] = *reinterpret_cast<const short8*>(&qp[(size_t)(q0 + lq) * DHD + d * 16 + hi * 8]);

  f32x16 oacc[2];
#pragma unroll
  for (int e = 0; e < 16; ++e) { oacc[0][e] = 0.f; oacc[1][e] = 0.f; }
  float m2 = -INFINITY, lsum = 0.f;

  const int kv_begin = wave * (SEQ / 4);
  const int kv_end = kv_begin + (SEQ / 4);
  for (int kv0 = kv_begin; kv0 < kv_end; kv0 += 64) {
    // S^T[kv][q] accumulated over d; lane holds col q=lq, rows kv=(e&3)+8*(e>>2)+4*hi (+32*h2)
    f32x16 st[2];
#pragma unroll
    for (int h2 = 0; h2 < 2; ++h2) {
      f32x16 z;
#pragma unroll
      for (int e = 0; e < 16; ++e) z[e] = 0.f;
#pragma unroll
      for (int d = 0; d < 4; ++d) {
        short8 ak = *reinterpret_cast<const short8*>(
            &kp[(size_t)(kv0 + h2 * 32 + lq) * DHD + d * 16 + hi * 8]);
        z = __builtin_amdgcn_mfma_f32_32x32x16_bf16(ak, qf[d], z, 0, 0, 0);
      }
      st[h2] = z;
    }
    // mask add (exp2 domain): p = s + mask*log2e
    float p[32];
#pragma unroll
    for (int h2 = 0; h2 < 2; ++h2)
#pragma unroll
      for (int g = 0; g < 4; ++g) {
        f32x4 mv = *reinterpret_cast<const f32x4*>(&mrow[kv0 + h2 * 32 + g * 8 + hi * 4]);
#pragma unroll
        for (int j = 0; j < 4; ++j)
          p[h2 * 16 + g * 4 + j] = fmaf(mv[j], L2E, st[h2][g * 4 + j]);
      }
    // row max: in-register tree + one cross-half exchange
    float t8[8];
#pragma unroll
    for (int i = 0; i < 8; ++i)
      t8[i] = fmaxf(fmaxf(p[i], p[i + 8]), fmaxf(p[i + 16], p[i + 24]));
#pragma unroll
    for (int i = 0; i < 4; ++i) t8[i] = fmaxf(t8[i], t8[i + 4]);
    float mt = fmaxf(fmaxf(t8[0], t8[1]), fmaxf(t8[2], t8[3]));
    mt = fmaxf(mt, __shfl_xor(mt, 32));
    const float mnew = fmaxf(m2, mt);
    const float alpha = __builtin_amdgcn_exp2f(m2 - mnew);
    m2 = mnew;
#pragma unroll
    for (int i = 0; i < 32; ++i) p[i] = __builtin_amdgcn_exp2f(p[i] - m2);
    float s8[8];
#pragma unroll
    for (int i = 0; i < 8; ++i) s8[i] = (p[i] + p[i + 8]) + (p[i + 16] + p[i + 24]);
#pragma unroll
    for (int i = 0; i < 4; ++i) s8[i] += s8[i + 4];
    float ssum = (s8[0] + s8[1]) + (s8[2] + s8[3]);
    ssum += __shfl_xor(ssum, 32);
    lsum = lsum * alpha + ssum;
#pragma unroll
    for (int e = 0; e < 16; ++e) { oacc[0][e] *= alpha; oacc[1][e] *= alpha; }

    // P^T fragments (B-operand) via pack + permlane32_swap; O^T += V^T . P^T
#pragma unroll
    for (int kb = 0; kb < 4; ++kb) {
      const int pb = (kb >> 1) * 16 + (kb & 1) * 8;
      u32 x = pack2bf(p[pb + 0], p[pb + 1]);
      u32 y = pack2bf(p[pb + 4], p[pb + 5]);
      asm volatile("v_permlane32_swap_b32 %0, %1" : "+v"(x), "+v"(y));
      u32 zz = pack2bf(p[pb + 2], p[pb + 3]);
      u32 w = pack2bf(p[pb + 6], p[pb + 7]);
      asm volatile("v_permlane32_swap_b32 %0, %1" : "+v"(zz), "+v"(w));
      union { u32 u[4]; short8 s; } bf;
      bf.u[0] = x; bf.u[1] = zz; bf.u[2] = y; bf.u[3] = w;
#pragma unroll
      for (int db = 0; db < 2; ++db) {
        short8 av = *reinterpret_cast<const short8*>(
            &vp[(size_t)(db * 32 + lq) * SEQ + kv0 + kb * 16 + hi * 8]);
        oacc[db] = __builtin_amdgcn_mfma_f32_32x32x16_bf16(av, bf.s, oacc[db], 0, 0, 0);
      }
    }
  }

  // ---- cross-wave combine of (m, l, O) partials ----
  if (hi == 0) mred[wave][lq] = m2;
  __syncthreads();
  const float M = fmaxf(fmaxf(mred[0][lq], mred[1][lq]), fmaxf(mred[2][lq], mred[3][lq]));
  const float beta = __builtin_amdgcn_exp2f(m2 - M);
#pragma unroll
  for (int e = 0; e < 16; ++e) { oacc[0][e] *= beta; oacc[1][e] *= beta; }
  if (hi == 0) lred[wave][lq] = lsum * beta;

#pragma unroll
  for (int w = 0; w < 4; ++w) {
    if (wave == w) {
#pragma unroll
      for (int db = 0; db < 2; ++db)
#pragma unroll
        for (int e = 0; e < 16; ++e) {
          const int d = db * 32 + (e & 3) + 8 * (e >> 2) + 4 * hi;
          if (w == 0) O_l[lq][d] = oacc[db][e];
          else        O_l[lq][d] += oacc[db][e];
        }
    }
    __syncthreads();
  }

  // ---- store: O in [B,S,H,DH] bf16; each thread handles 8 consecutive d of one q-row
  const int b = bh >> 4, h = bh & 15;
  const int q = threadIdx.x >> 3;
  const int d0 = (threadIdx.x & 7) * 8;
  const float linv = 1.0f / (lred[0][q] + lred[1][q] + lred[2][q] + lred[3][q]);
  union { u16 u[8]; short8 s; } pk;
#pragma unroll
  for (int j = 0; j < 8; ++j) pk.u[j] = f2bf(O_l[q][d0 + j] * linv);
  *reinterpret_cast<short8*>(&O[((size_t)(b * SEQ + q0 + q) * NH + h) * DHD + d0]) = pk.s;
}

// ---- output projection: d_out = O @ Wo^T + bo (fp32 out)
__global__ __launch_bounds__(256) void out_proj_kernel(
    const u16* __restrict__ O, const float* __restrict__ Wo, const float* __restrict__ bo,
    float* __restrict__ out) {
  __shared__ u16 As[128 * 32];
  __shared__ u16 Bs[128 * 32];
  const int m0 = blockIdx.y * 128, n0 = blockIdx.x * 128;
  f32x4 acc[4][4];
  gemm_bt_body(O, Wo, m0, n0, As, Bs, acc);

  const int lane = threadIdx.x & 63;
  const int wr = (threadIdx.x >> 7) & 1, wc = (threadIdx.x >> 6) & 1;
  const int rbase = m0 + wr * 64 + ((lane >> 4) << 2);
  const int cbase = n0 + wc * 64 + (lane & 15);
#pragma unroll
  for (int n = 0; n < 4; ++n) {
    const int col = cbase + n * 16;
    const float bvv = bo[col];
#pragma unroll
    for (int m = 0; m < 4; ++m)
#pragma unroll
      for (int r = 0; r < 4; ++r) {
        const int row = rbase + m * 16 + r;
        out[(size_t)row * FD + col] = acc[m][n][r] + bvv;
      }
  }
}

extern "C" void kernel_launch(void* const* d_in, const int* in_sizes, int n_in,
                              void* d_out, int out_size, void* d_ws, size_t ws_size,
                              hipStream_t stream) {
  (void)in_sizes; (void)n_in; (void)out_size; (void)ws_size;
  const float* Q    = (const float*)d_in[0];
  const float* K    = (const float*)d_in[1];
  const float* V    = (const float*)d_in[2];
  const float* mask = (const float*)d_in[3];
  const float* Wq   = (const float*)d_in[4];
  const float* bq   = (const float*)d_in[5];
  const float* Wk   = (const float*)d_in[6];
  const float* bk   = (const float*)d_in[7];
  const float* Wv   = (const float*)d_in[8];
  const float* bv   = (const float*)d_in[9];
  const float* Wo   = (const float*)d_in[10];
  const float* bo   = (const float*)d_in[11];
  float* out = (float*)d_out;

  u16* ws = (u16*)d_ws;
  const size_t SZ = (size_t)4096 * 1024;   // B*S*F elements
  u16* qh = ws;            // [B,H,S,DH] bf16 (pre-scaled by 0.125*log2e)
  u16* kh = qh + SZ;       // [B,H,S,DH] bf16
  u16* vT = kh + SZ;       // [B,H,DH,S] bf16
  u16* O  = vT + SZ;       // [B,S,H,DH] bf16

  dim3 gproj(FD / 128, (2 * SEQ) / 128, 3);      // (8, 32, 3)
  proj_qkv_kernel<<<gproj, 256, 0, stream>>>(Q, K, V, Wq, Wk, Wv, bq, bk, bv, qh, kh, vT);

  attn_kernel<<<dim3(2048), 256, 0, stream>>>(qh, kh, vT, mask, O);

  out_proj_kernel<<<dim3(FD / 128, (2 * SEQ) / 128), 256, 0, stream>>>(O, Wo, bo, out);
}

// Round 5
// 236.682 us; speedup vs baseline: 4.4810x; 1.2598x over previous
//
#include <hip/hip_runtime.h>
#include <hip/hip_bf16.h>

typedef unsigned short u16;
typedef unsigned int u32;
typedef __attribute__((ext_vector_type(4))) float f32x4;
typedef __attribute__((ext_vector_type(16))) float f32x16;
typedef __attribute__((ext_vector_type(8))) short short8;
typedef __attribute__((ext_vector_type(4))) u32 u32x4;

#define SEQ 2048
#define FD  1024
#define NH  16
#define DHD 64

__device__ __forceinline__ u16 f2bf(float f) {
  __hip_bfloat16 h = __float2bfloat16(f);
  return *reinterpret_cast<u16*>(&h);
}
__device__ __forceinline__ u32 pack2bf(float lo, float hi) {
  return (u32)f2bf(lo) | ((u32)f2bf(hi) << 16);
}

// ---- shared GEMM body: 128x128 tile of C = A[M,K] * B[N,K]^T (K-major both),
// bf16 MFMA 16x16x32, fp32 accum. A/B staged (with fp32->bf16 cvt if needed).
template <typename TA, typename TB>
__device__ __forceinline__ void gemm_bt_body(const TA* __restrict__ A, const TB* __restrict__ Bm,
                                             int m0, int n0, u16* As, u16* Bs, f32x4 acc[4][4]) {
  const int tid = threadIdx.x;
  const int lane = tid & 63;
  const int wr = (tid >> 7) & 1;   // wave row quadrant
  const int wc = (tid >> 6) & 1;   // wave col quadrant
  const int lr = lane & 15;
  const int lk = (lane >> 4) << 3;
#pragma unroll
  for (int m = 0; m < 4; ++m)
#pragma unroll
    for (int n = 0; n < 4; ++n) acc[m][n] = {0.f, 0.f, 0.f, 0.f};

  const int r_ = tid >> 2;
  const int c_ = (tid & 3) << 3;

  for (int k0 = 0; k0 < FD; k0 += 32) {
    __syncthreads();
#pragma unroll
    for (int c = 0; c < 2; ++c) {   // stage A tile half (64 rows x 32 cols)
      int r = c * 64 + r_;
      const TA* s = A + (size_t)(m0 + r) * FD + k0 + c_;
      short8 o;
      if constexpr (sizeof(TA) == 4) {
        f32x4 v0 = *reinterpret_cast<const f32x4*>(s);
        f32x4 v1 = *reinterpret_cast<const f32x4*>(s + 4);
#pragma unroll
        for (int j = 0; j < 4; ++j) { o[j] = (short)f2bf(v0[j]); o[4 + j] = (short)f2bf(v1[j]); }
      } else {
        o = *reinterpret_cast<const short8*>(s);
      }
      *reinterpret_cast<short8*>(&As[r * 32 + c_]) = o;
    }
#pragma unroll
    for (int c = 0; c < 2; ++c) {   // stage B tile half
      int r = c * 64 + r_;
      const TB* s = Bm + (size_t)(n0 + r) * FD + k0 + c_;
      short8 o;
      if constexpr (sizeof(TB) == 4) {
        f32x4 v0 = *reinterpret_cast<const f32x4*>(s);
        f32x4 v1 = *reinterpret_cast<const f32x4*>(s + 4);
#pragma unroll
        for (int j = 0; j < 4; ++j) { o[j] = (short)f2bf(v0[j]); o[4 + j] = (short)f2bf(v1[j]); }
      } else {
        o = *reinterpret_cast<const short8*>(s);
      }
      *reinterpret_cast<short8*>(&Bs[r * 32 + c_]) = o;
    }
    __syncthreads();

    short8 a[4], b[4];
#pragma unroll
    for (int m = 0; m < 4; ++m)
      a[m] = *reinterpret_cast<const short8*>(&As[(wr * 64 + m * 16 + lr) * 32 + lk]);
#pragma unroll
    for (int n = 0; n < 4; ++n)
      b[n] = *reinterpret_cast<const short8*>(&Bs[(wc * 64 + n * 16 + lr) * 32 + lk]);
#pragma unroll
    for (int m = 0; m < 4; ++m)
#pragma unroll
      for (int n = 0; n < 4; ++n)
        acc[m][n] = __builtin_amdgcn_mfma_f32_16x16x32_bf16(a[m], b[n], acc[m][n], 0, 0, 0);
  }
}

// ---- fused QKV projection. q -> [B,H,S,DH] bf16 (pre-scaled by 0.125*log2e).
// k, v -> FRAGMENT-MAJOR layouts so attention loads are wave-contiguous 1KB:
//  K': [bh][s/32][dh/16][lane(64)][8]  where lane=(dh>>3 &1)*32 + (s&31), elem j=dh&7
//  V': [bh][s/16][dh/32][lane(64)][8]  where lane=(s>>3 &1)*32 + (dh&31), elem j=s&7
__global__ __launch_bounds__(256) void proj_qkv_kernel(
    const float* __restrict__ Q, const float* __restrict__ K, const float* __restrict__ V,
    const float* __restrict__ Wq, const float* __restrict__ Wk, const float* __restrict__ Wv,
    const float* __restrict__ bq, const float* __restrict__ bk, const float* __restrict__ bv,
    u16* __restrict__ qh, u16* __restrict__ kh, u16* __restrict__ vF) {
  __shared__ u16 As[128 * 32];
  __shared__ u16 Bs[128 * 32];
  const int which = blockIdx.z;
  const float* A    = (which == 0) ? Q  : (which == 1) ? K  : V;
  const float* W    = (which == 0) ? Wq : (which == 1) ? Wk : Wv;
  const float* bias = (which == 0) ? bq : (which == 1) ? bk : bv;
  u16* out          = (which == 0) ? qh : (which == 1) ? kh : vF;
  const int m0 = blockIdx.y * 128, n0 = blockIdx.x * 128;
  const float qscale = 0.18033688011112042f;  // (1/8) * log2(e)

  f32x4 acc[4][4];
  gemm_bt_body(A, W, m0, n0, As, Bs, acc);

  const int lane = threadIdx.x & 63;
  const int wr = (threadIdx.x >> 7) & 1, wc = (threadIdx.x >> 6) & 1;
  const int rbase = m0 + wr * 64 + ((lane >> 4) << 2);
  const int cbase = n0 + wc * 64 + (lane & 15);
#pragma unroll
  for (int n = 0; n < 4; ++n) {
    const int col = cbase + n * 16;
    const float bvv = bias[col];
    const int h = col >> 6, dh = col & 63;
#pragma unroll
    for (int m = 0; m < 4; ++m) {
#pragma unroll
      for (int r = 0; r < 4; ++r) {
        const int row = rbase + m * 16 + r;
        const int b = row >> 11, s = row & 2047;
        float v = acc[m][n][r] + bvv;
        if (which == 0) v *= qscale;
        const size_t bhbase = (size_t)(b * 16 + h) * SEQ * DHD;
        size_t idx;
        if (which == 0) {
          idx = bhbase + (size_t)s * 64 + dh;                                   // [B,H,S,DH]
        } else if (which == 1) {
          idx = bhbase + ((size_t)(((s >> 5) * 4 + (dh >> 4)) * 64
                          + ((dh >> 3) & 1) * 32 + (s & 31)) << 3) + (dh & 7);  // K' frag
        } else {
          idx = bhbase + ((size_t)(((s >> 4) * 2 + (dh >> 5)) * 64
                          + ((s >> 3) & 1) * 32 + (dh & 31)) << 3) + (s & 7);   // V' frag
        }
        out[idx] = f2bf(v);
      }
    }
  }
}

// ---- mask zero-check: OR all mask bits into flag (flag pre-zeroed via memset)
__global__ __launch_bounds__(256) void mask_check_kernel(const u32* __restrict__ mask,
                                                         u32* __restrict__ flag) {
  const size_t cb = (size_t)blockIdx.x * 2048 + (threadIdx.x << 2);
  u32x4 a = *reinterpret_cast<const u32x4*>(&mask[cb]);
  u32x4 b = *reinterpret_cast<const u32x4*>(&mask[cb + 1024]);
  u32 acc = a[0] | a[1] | a[2] | a[3] | b[0] | b[1] | b[2] | b[3];
  if (__ballot(acc != 0)) {
    if ((threadIdx.x & 63) == 0) atomicOr(flag, 1u);
  }
}

// ---- flash attention, swapped-operand 32x32, 4-way KV split per block.
// K/V loads are wave-contiguous 1KB from fragment-major layouts; mask loads
// skipped entirely when *mflag==0 (uniform branch; slow scattered path kept
// for correctness with nonzero masks).
__global__ __launch_bounds__(256, 4) void attn_kernel(
    const u16* __restrict__ qh, const u16* __restrict__ kh, const u16* __restrict__ vF,
    const float* __restrict__ mask, const u32* __restrict__ mflag, u16* __restrict__ O) {
  __shared__ float mred[4][32];
  __shared__ float lred[4][32];
  __shared__ float O_l[32][65];   // stride 65 -> worst 2-way (free) conflicts
  const int wave = threadIdx.x >> 6, lane = threadIdx.x & 63;
  const int bh = blockIdx.x >> 6;
  const int q0 = (blockIdx.x & 63) * 32;
  const int lq = lane & 31;
  const int hi = lane >> 5;
  const u16* qp = qh + (size_t)bh * SEQ * DHD;
  const u16* kp = kh + (size_t)bh * SEQ * DHD;
  const u16* vp = vF + (size_t)bh * SEQ * DHD;
  const float* mrow = mask + (size_t)(q0 + lq) * SEQ;
  const float L2E = 1.44269504088896340736f;
  const u32 has_mask = *mflag;

  short8 qf[4];
#pragma unroll
  for (int d = 0; d < 4; ++d)
    qf[d] = *reinterpret_cast<const short8*>(&qp[(size_t)(q0 + lq) * DHD + d * 16 + hi * 8]);

  f32x16 oacc[2];
#pragma unroll
  for (int e = 0; e < 16; ++e) { oacc[0][e] = 0.f; oacc[1][e] = 0.f; }
  float m2 = -INFINITY, lsum = 0.f;

  const int kv_begin = wave * (SEQ / 4);
  const int kv_end = kv_begin + (SEQ / 4);
  for (int kv0 = kv_begin; kv0 < kv_end; kv0 += 64) {
    // S^T[kv][q] accumulated over d; lane holds col q=lq, rows kv=(e&3)+8*(e>>2)+4*hi (+32*h2)
    f32x16 st[2];
#pragma unroll
    for (int h2 = 0; h2 < 2; ++h2) {
      f32x16 z;
#pragma unroll
      for (int e = 0; e < 16; ++e) z[e] = 0.f;
#pragma unroll
      for (int d = 0; d < 4; ++d) {
        // K' fragment: contiguous 64 lanes x 16B
        short8 ak = *reinterpret_cast<const short8*>(
            &kp[((size_t)((((kv0 >> 5) + h2) * 4 + d) * 64 + lane)) << 3]);
        z = __builtin_amdgcn_mfma_f32_32x32x16_bf16(ak, qf[d], z, 0, 0, 0);
      }
      st[h2] = z;
    }
    float p[32];
    if (__builtin_expect(has_mask != 0, 0)) {
      // slow path: scattered per-q-row mask loads (correct for any mask)
#pragma unroll
      for (int h2 = 0; h2 < 2; ++h2)
#pragma unroll
        for (int g = 0; g < 4; ++g) {
          f32x4 mv = *reinterpret_cast<const f32x4*>(&mrow[kv0 + h2 * 32 + g * 8 + hi * 4]);
#pragma unroll
          for (int j = 0; j < 4; ++j)
            p[h2 * 16 + g * 4 + j] = fmaf(mv[j], L2E, st[h2][g * 4 + j]);
        }
    } else {
#pragma unroll
      for (int h2 = 0; h2 < 2; ++h2)
#pragma unroll
        for (int e = 0; e < 16; ++e) p[h2 * 16 + e] = st[h2][e];
    }
    // row max: in-register tree + one cross-half exchange
    float t8[8];
#pragma unroll
    for (int i = 0; i < 8; ++i)
      t8[i] = fmaxf(fmaxf(p[i], p[i + 8]), fmaxf(p[i + 16], p[i + 24]));
#pragma unroll
    for (int i = 0; i < 4; ++i) t8[i] = fmaxf(t8[i], t8[i + 4]);
    float mt = fmaxf(fmaxf(t8[0], t8[1]), fmaxf(t8[2], t8[3]));
    mt = fmaxf(mt, __shfl_xor(mt, 32));
    const float mnew = fmaxf(m2, mt);
    const float alpha = __builtin_amdgcn_exp2f(m2 - mnew);
    m2 = mnew;
#pragma unroll
    for (int i = 0; i < 32; ++i) p[i] = __builtin_amdgcn_exp2f(p[i] - m2);
    float s8[8];
#pragma unroll
    for (int i = 0; i < 8; ++i) s8[i] = (p[i] + p[i + 8]) + (p[i + 16] + p[i + 24]);
#pragma unroll
    for (int i = 0; i < 4; ++i) s8[i] += s8[i + 4];
    float ssum = (s8[0] + s8[1]) + (s8[2] + s8[3]);
    ssum += __shfl_xor(ssum, 32);
    lsum = lsum * alpha + ssum;
#pragma unroll
    for (int e = 0; e < 16; ++e) { oacc[0][e] *= alpha; oacc[1][e] *= alpha; }

    // P^T fragments (B-operand) via pack + permlane32_swap; O^T += V^T . P^T
#pragma unroll
    for (int kb = 0; kb < 4; ++kb) {
      const int pb = (kb >> 1) * 16 + (kb & 1) * 8;
      u32 x = pack2bf(p[pb + 0], p[pb + 1]);
      u32 y = pack2bf(p[pb + 4], p[pb + 5]);
      asm volatile("v_permlane32_swap_b32 %0, %1" : "+v"(x), "+v"(y));
      u32 zz = pack2bf(p[pb + 2], p[pb + 3]);
      u32 w = pack2bf(p[pb + 6], p[pb + 7]);
      asm volatile("v_permlane32_swap_b32 %0, %1" : "+v"(zz), "+v"(w));
      union { u32 u[4]; short8 s; } bf;
      bf.u[0] = x; bf.u[1] = zz; bf.u[2] = y; bf.u[3] = w;
#pragma unroll
      for (int db = 0; db < 2; ++db) {
        // V' fragment: contiguous 64 lanes x 16B
        short8 av = *reinterpret_cast<const short8*>(
            &vp[((size_t)((((kv0 >> 4) + kb) * 2 + db) * 64 + lane)) << 3]);
        oacc[db] = __builtin_amdgcn_mfma_f32_32x32x16_bf16(av, bf.s, oacc[db], 0, 0, 0);
      }
    }
  }

  // ---- cross-wave combine of (m, l, O) partials ----
  if (hi == 0) mred[wave][lq] = m2;
  __syncthreads();
  const float M = fmaxf(fmaxf(mred[0][lq], mred[1][lq]), fmaxf(mred[2][lq], mred[3][lq]));
  const float beta = __builtin_amdgcn_exp2f(m2 - M);
#pragma unroll
  for (int e = 0; e < 16; ++e) { oacc[0][e] *= beta; oacc[1][e] *= beta; }
  if (hi == 0) lred[wave][lq] = lsum * beta;

#pragma unroll
  for (int w = 0; w < 4; ++w) {
    if (wave == w) {
#pragma unroll
      for (int db = 0; db < 2; ++db)
#pragma unroll
        for (int e = 0; e < 16; ++e) {
          const int d = db * 32 + (e & 3) + 8 * (e >> 2) + 4 * hi;
          if (w == 0) O_l[lq][d] = oacc[db][e];
          else        O_l[lq][d] += oacc[db][e];
        }
    }
    __syncthreads();
  }

  // ---- store: O in [B,S,H,DH] bf16; each thread handles 8 consecutive d of one q-row
  const int b = bh >> 4, h = bh & 15;
  const int q = threadIdx.x >> 3;
  const int d0 = (threadIdx.x & 7) * 8;
  const float linv = 1.0f / (lred[0][q] + lred[1][q] + lred[2][q] + lred[3][q]);
  union { u16 u[8]; short8 s; } pk;
#pragma unroll
  for (int j = 0; j < 8; ++j) pk.u[j] = f2bf(O_l[q][d0 + j] * linv);
  *reinterpret_cast<short8*>(&O[((size_t)(b * SEQ + q0 + q) * NH + h) * DHD + d0]) = pk.s;
}

// ---- output projection: d_out = O @ Wo^T + bo (fp32 out)
__global__ __launch_bounds__(256) void out_proj_kernel(
    const u16* __restrict__ O, const float* __restrict__ Wo, const float* __restrict__ bo,
    float* __restrict__ out) {
  __shared__ u16 As[128 * 32];
  __shared__ u16 Bs[128 * 32];
  const int m0 = blockIdx.y * 128, n0 = blockIdx.x * 128;
  f32x4 acc[4][4];
  gemm_bt_body(O, Wo, m0, n0, As, Bs, acc);

  const int lane = threadIdx.x & 63;
  const int wr = (threadIdx.x >> 7) & 1, wc = (threadIdx.x >> 6) & 1;
  const int rbase = m0 + wr * 64 + ((lane >> 4) << 2);
  const int cbase = n0 + wc * 64 + (lane & 15);
#pragma unroll
  for (int n = 0; n < 4; ++n) {
    const int col = cbase + n * 16;
    const float bvv = bo[col];
#pragma unroll
    for (int m = 0; m < 4; ++m)
#pragma unroll
      for (int r = 0; r < 4; ++r) {
        const int row = rbase + m * 16 + r;
        out[(size_t)row * FD + col] = acc[m][n][r] + bvv;
      }
  }
}

extern "C" void kernel_launch(void* const* d_in, const int* in_sizes, int n_in,
                              void* d_out, int out_size, void* d_ws, size_t ws_size,
                              hipStream_t stream) {
  (void)in_sizes; (void)n_in; (void)out_size; (void)ws_size;
  const float* Q    = (const float*)d_in[0];
  const float* K    = (const float*)d_in[1];
  const float* V    = (const float*)d_in[2];
  const float* mask = (const float*)d_in[3];
  const float* Wq   = (const float*)d_in[4];
  const float* bq   = (const float*)d_in[5];
  const float* Wk   = (const float*)d_in[6];
  const float* bk   = (const float*)d_in[7];
  const float* Wv   = (const float*)d_in[8];
  const float* bv   = (const float*)d_in[9];
  const float* Wo   = (const float*)d_in[10];
  const float* bo   = (const float*)d_in[11];
  float* out = (float*)d_out;

  u16* ws = (u16*)d_ws;
  const size_t SZ = (size_t)4096 * 1024;   // B*S*F elements
  u16* qh = ws;            // [B,H,S,DH] bf16 (pre-scaled by 0.125*log2e)
  u16* kh = qh + SZ;       // K' fragment-major bf16
  u16* vF = kh + SZ;       // V' fragment-major bf16
  u16* O  = vF + SZ;       // [B,S,H,DH] bf16
  u32* mflag = (u32*)(O + SZ);

  hipMemsetAsync(mflag, 0, 4, stream);
  mask_check_kernel<<<dim3(2048), 256, 0, stream>>>((const u32*)mask, mflag);

  dim3 gproj(FD / 128, (2 * SEQ) / 128, 3);      // (8, 32, 3)
  proj_qkv_kernel<<<gproj, 256, 0, stream>>>(Q, K, V, Wq, Wk, Wv, bq, bk, bv, qh, kh, vF);

  attn_kernel<<<dim3(2048), 256, 0, stream>>>(qh, kh, vF, mask, mflag, O);

  out_proj_kernel<<<dim3(FD / 128, (2 * SEQ) / 128), 256, 0, stream>>>(O, Wo, bo, out);
}

// Round 6
// 169.315 us; speedup vs baseline: 6.2639x; 1.3979x over previous
//
#include <hip/hip_runtime.h>
#include <hip/hip_bf16.h>

typedef unsigned short u16;
typedef unsigned int u32;
typedef __attribute__((ext_vector_type(4))) float f32x4;
typedef __attribute__((ext_vector_type(16))) float f32x16;
typedef __attribute__((ext_vector_type(8))) short short8;
typedef __attribute__((ext_vector_type(4))) u32 u32x4;

#define SEQ 2048
#define FD  1024
#define NH  16
#define DHD 64

__device__ __forceinline__ u16 f2bf(float f) {
  __hip_bfloat16 h = __float2bfloat16(f);
  return *reinterpret_cast<u16*>(&h);
}
__device__ __forceinline__ u32 pack2bf(float lo, float hi) {
  return (u32)f2bf(lo) | ((u32)f2bf(hi) << 16);
}

// ---- shared GEMM body: 128x128 tile of C = A[M,K] * B[N,K]^T (K-major both),
// bf16 MFMA 16x16x32, fp32 accum. A/B staged (with fp32->bf16 cvt if needed).
template <typename TA, typename TB>
__device__ __forceinline__ void gemm_bt_body(const TA* __restrict__ A, const TB* __restrict__ Bm,
                                             int m0, int n0, u16* As, u16* Bs, f32x4 acc[4][4]) {
  const int tid = threadIdx.x;
  const int lane = tid & 63;
  const int wr = (tid >> 7) & 1;   // wave row quadrant
  const int wc = (tid >> 6) & 1;   // wave col quadrant
  const int lr = lane & 15;
  const int lk = (lane >> 4) << 3;
#pragma unroll
  for (int m = 0; m < 4; ++m)
#pragma unroll
    for (int n = 0; n < 4; ++n) acc[m][n] = {0.f, 0.f, 0.f, 0.f};

  const int r_ = tid >> 2;
  const int c_ = (tid & 3) << 3;

  for (int k0 = 0; k0 < FD; k0 += 32) {
    __syncthreads();
#pragma unroll
    for (int c = 0; c < 2; ++c) {   // stage A tile half (64 rows x 32 cols)
      int r = c * 64 + r_;
      const TA* s = A + (size_t)(m0 + r) * FD + k0 + c_;
      short8 o;
      if constexpr (sizeof(TA) == 4) {
        f32x4 v0 = *reinterpret_cast<const f32x4*>(s);
        f32x4 v1 = *reinterpret_cast<const f32x4*>(s + 4);
#pragma unroll
        for (int j = 0; j < 4; ++j) { o[j] = (short)f2bf(v0[j]); o[4 + j] = (short)f2bf(v1[j]); }
      } else {
        o = *reinterpret_cast<const short8*>(s);
      }
      *reinterpret_cast<short8*>(&As[r * 32 + c_]) = o;
    }
#pragma unroll
    for (int c = 0; c < 2; ++c) {   // stage B tile half
      int r = c * 64 + r_;
      const TB* s = Bm + (size_t)(n0 + r) * FD + k0 + c_;
      short8 o;
      if constexpr (sizeof(TB) == 4) {
        f32x4 v0 = *reinterpret_cast<const f32x4*>(s);
        f32x4 v1 = *reinterpret_cast<const f32x4*>(s + 4);
#pragma unroll
        for (int j = 0; j < 4; ++j) { o[j] = (short)f2bf(v0[j]); o[4 + j] = (short)f2bf(v1[j]); }
      } else {
        o = *reinterpret_cast<const short8*>(s);
      }
      *reinterpret_cast<short8*>(&Bs[r * 32 + c_]) = o;
    }
    __syncthreads();

    short8 a[4], b[4];
#pragma unroll
    for (int m = 0; m < 4; ++m)
      a[m] = *reinterpret_cast<const short8*>(&As[(wr * 64 + m * 16 + lr) * 32 + lk]);
#pragma unroll
    for (int n = 0; n < 4; ++n)
      b[n] = *reinterpret_cast<const short8*>(&Bs[(wc * 64 + n * 16 + lr) * 32 + lk]);
#pragma unroll
    for (int m = 0; m < 4; ++m)
#pragma unroll
      for (int n = 0; n < 4; ++n)
        acc[m][n] = __builtin_amdgcn_mfma_f32_16x16x32_bf16(a[m], b[n], acc[m][n], 0, 0, 0);
  }
}

// ---- fused QKV projection. q -> [B,H,S,DH] bf16 (pre-scaled by 0.125*log2e).
// k, v -> FRAGMENT-MAJOR layouts so attention loads are wave-contiguous 1KB:
//  K': [bh][s/32][dh/16][lane(64)][8]  where lane=(dh>>3 &1)*32 + (s&31), elem j=dh&7
//  V': [bh][s/16][dh/32][lane(64)][8]  where lane=(s>>3 &1)*32 + (dh&31), elem j=s&7
__global__ __launch_bounds__(256) void proj_qkv_kernel(
    const float* __restrict__ Q, const float* __restrict__ K, const float* __restrict__ V,
    const float* __restrict__ Wq, const float* __restrict__ Wk, const float* __restrict__ Wv,
    const float* __restrict__ bq, const float* __restrict__ bk, const float* __restrict__ bv,
    u16* __restrict__ qh, u16* __restrict__ kh, u16* __restrict__ vF) {
  __shared__ u16 As[128 * 32];
  __shared__ u16 Bs[128 * 32];
  const int which = blockIdx.z;
  const float* A    = (which == 0) ? Q  : (which == 1) ? K  : V;
  const float* W    = (which == 0) ? Wq : (which == 1) ? Wk : Wv;
  const float* bias = (which == 0) ? bq : (which == 1) ? bk : bv;
  u16* out          = (which == 0) ? qh : (which == 1) ? kh : vF;
  const int m0 = blockIdx.y * 128, n0 = blockIdx.x * 128;
  const float qscale = 0.18033688011112042f;  // (1/8) * log2(e)

  f32x4 acc[4][4];
  gemm_bt_body(A, W, m0, n0, As, Bs, acc);

  const int lane = threadIdx.x & 63;
  const int wr = (threadIdx.x >> 7) & 1, wc = (threadIdx.x >> 6) & 1;
  const int rbase = m0 + wr * 64 + ((lane >> 4) << 2);
  const int cbase = n0 + wc * 64 + (lane & 15);
#pragma unroll
  for (int n = 0; n < 4; ++n) {
    const int col = cbase + n * 16;
    const float bvv = bias[col];
    const int h = col >> 6, dh = col & 63;
#pragma unroll
    for (int m = 0; m < 4; ++m) {
#pragma unroll
      for (int r = 0; r < 4; ++r) {
        const int row = rbase + m * 16 + r;
        const int b = row >> 11, s = row & 2047;
        float v = acc[m][n][r] + bvv;
        if (which == 0) v *= qscale;
        const size_t bhbase = (size_t)(b * 16 + h) * SEQ * DHD;
        size_t idx;
        if (which == 0) {
          idx = bhbase + (size_t)s * 64 + dh;                                   // [B,H,S,DH]
        } else if (which == 1) {
          idx = bhbase + ((size_t)(((s >> 5) * 4 + (dh >> 4)) * 64
                          + ((dh >> 3) & 1) * 32 + (s & 31)) << 3) + (dh & 7);  // K' frag
        } else {
          idx = bhbase + ((size_t)(((s >> 4) * 2 + (dh >> 5)) * 64
                          + ((s >> 3) & 1) * 32 + (dh & 31)) << 3) + (s & 7);   // V' frag
        }
        out[idx] = f2bf(v);
      }
    }
  }
}

// ---- mask zero-check: OR all mask bits into flag (flag pre-zeroed via memset)
__global__ __launch_bounds__(256) void mask_check_kernel(const u32* __restrict__ mask,
                                                         u32* __restrict__ flag) {
  const size_t cb = (size_t)blockIdx.x * 2048 + (threadIdx.x << 2);
  u32x4 a = *reinterpret_cast<const u32x4*>(&mask[cb]);
  u32x4 b = *reinterpret_cast<const u32x4*>(&mask[cb + 1024]);
  u32 acc = a[0] | a[1] | a[2] | a[3] | b[0] | b[1] | b[2] | b[3];
  if (__ballot(acc != 0)) {
    if ((threadIdx.x & 63) == 0) atomicOr(flag, 1u);
  }
}

__device__ __forceinline__ void load_ktile(const u16* __restrict__ kp, int kv0, int lane,
                                           short8 (&kf)[8]) {
#pragma unroll
  for (int h2 = 0; h2 < 2; ++h2)
#pragma unroll
    for (int d = 0; d < 4; ++d)
      kf[h2 * 4 + d] = *reinterpret_cast<const short8*>(
          &kp[((size_t)((((kv0 >> 5) + h2) * 4 + d) * 64 + lane)) << 3]);
}

// one 32q x 64kv tile: V loads issued first (hide under QK+softmax), K regs pre-loaded
__device__ __forceinline__ void attn_tile(
    const short8 (&kf)[8], const u16* __restrict__ vp, const float* __restrict__ mrow,
    u32 has_mask, int kv0, int lane, int hi, const short8 (&qf)[4],
    f32x16 (&oacc)[2], float& m2, float& lsum) {
  const float L2E = 1.44269504088896340736f;
  // V' fragment loads for THIS tile (consumed after softmax)
  short8 vf[8];
#pragma unroll
  for (int kb = 0; kb < 4; ++kb)
#pragma unroll
    for (int db = 0; db < 2; ++db)
      vf[kb * 2 + db] = *reinterpret_cast<const short8*>(
          &vp[((size_t)((((kv0 >> 4) + kb) * 2 + db) * 64 + lane)) << 3]);

  // S^T = K . Q  (lane holds col q, rows kv=(e&3)+8*(e>>2)+4*hi (+32*h2))
  f32x16 st[2];
#pragma unroll
  for (int h2 = 0; h2 < 2; ++h2) {
    f32x16 z;
#pragma unroll
    for (int e = 0; e < 16; ++e) z[e] = 0.f;
#pragma unroll
    for (int d = 0; d < 4; ++d)
      z = __builtin_amdgcn_mfma_f32_32x32x16_bf16(kf[h2 * 4 + d], qf[d], z, 0, 0, 0);
    st[h2] = z;
  }
  float p[32];
  if (__builtin_expect(has_mask != 0, 0)) {
#pragma unroll
    for (int h2 = 0; h2 < 2; ++h2)
#pragma unroll
      for (int g = 0; g < 4; ++g) {
        f32x4 mv = *reinterpret_cast<const f32x4*>(&mrow[kv0 + h2 * 32 + g * 8 + hi * 4]);
#pragma unroll
        for (int j = 0; j < 4; ++j)
          p[h2 * 16 + g * 4 + j] = fmaf(mv[j], L2E, st[h2][g * 4 + j]);
      }
  } else {
#pragma unroll
    for (int h2 = 0; h2 < 2; ++h2)
#pragma unroll
      for (int e = 0; e < 16; ++e) p[h2 * 16 + e] = st[h2][e];
  }
  // row max: in-register tree + one cross-half exchange
  float t8[8];
#pragma unroll
  for (int i = 0; i < 8; ++i)
    t8[i] = fmaxf(fmaxf(p[i], p[i + 8]), fmaxf(p[i + 16], p[i + 24]));
#pragma unroll
  for (int i = 0; i < 4; ++i) t8[i] = fmaxf(t8[i], t8[i + 4]);
  float mt = fmaxf(fmaxf(t8[0], t8[1]), fmaxf(t8[2], t8[3]));
  mt = fmaxf(mt, __shfl_xor(mt, 32));
  const float mnew = fmaxf(m2, mt);
  const float alpha = __builtin_amdgcn_exp2f(m2 - mnew);
  m2 = mnew;
#pragma unroll
  for (int i = 0; i < 32; ++i) p[i] = __builtin_amdgcn_exp2f(p[i] - m2);
  float s8[8];
#pragma unroll
  for (int i = 0; i < 8; ++i) s8[i] = (p[i] + p[i + 8]) + (p[i + 16] + p[i + 24]);
#pragma unroll
  for (int i = 0; i < 4; ++i) s8[i] += s8[i + 4];
  float ssum = (s8[0] + s8[1]) + (s8[2] + s8[3]);
  ssum += __shfl_xor(ssum, 32);
  lsum = lsum * alpha + ssum;
#pragma unroll
  for (int e = 0; e < 16; ++e) { oacc[0][e] *= alpha; oacc[1][e] *= alpha; }

  // P^T fragments (B-operand) via pack + permlane32_swap; O^T += V^T . P^T
#pragma unroll
  for (int kb = 0; kb < 4; ++kb) {
    const int pb = (kb >> 1) * 16 + (kb & 1) * 8;
    u32 x = pack2bf(p[pb + 0], p[pb + 1]);
    u32 y = pack2bf(p[pb + 4], p[pb + 5]);
    asm volatile("v_permlane32_swap_b32 %0, %1" : "+v"(x), "+v"(y));
    u32 zz = pack2bf(p[pb + 2], p[pb + 3]);
    u32 w = pack2bf(p[pb + 6], p[pb + 7]);
    asm volatile("v_permlane32_swap_b32 %0, %1" : "+v"(zz), "+v"(w));
    union { u32 u[4]; short8 s; } bf;
    bf.u[0] = x; bf.u[1] = zz; bf.u[2] = y; bf.u[3] = w;
#pragma unroll
    for (int db = 0; db < 2; ++db)
      oacc[db] = __builtin_amdgcn_mfma_f32_32x32x16_bf16(vf[kb * 2 + db], bf.s, oacc[db], 0, 0, 0);
  }
}

// ---- flash attention: 128 q-rows/block (4 waves x 32q, full-KV loop each),
// XCD-swizzled so each XCD owns 4 complete heads (2MB K/V, L2-resident),
// K reg ping-pong prefetch across iterations. Zero LDS, no combine.
__global__ __launch_bounds__(256, 2) void attn_kernel(
    const u16* __restrict__ qh, const u16* __restrict__ kh, const u16* __restrict__ vF,
    const float* __restrict__ mask, const u32* __restrict__ mflag, u16* __restrict__ O) {
  const int wave = threadIdx.x >> 6, lane = threadIdx.x & 63;
  const int bid = blockIdx.x;
  const int vid = (bid & 7) * 64 + (bid >> 3);   // XCD x gets vids [x*64,(x+1)*64) = 4 heads
  const int bh = vid >> 4;
  const int q0 = (vid & 15) * 128 + wave * 32;
  const int lq = lane & 31;
  const int hi = lane >> 5;
  const u16* qp = qh + (size_t)bh * SEQ * DHD;
  const u16* kp = kh + (size_t)bh * SEQ * DHD;
  const u16* vp = vF + (size_t)bh * SEQ * DHD;
  const float* mrow = mask + (size_t)(q0 + lq) * SEQ;
  const u32 has_mask = *mflag;

  short8 qf[4];
#pragma unroll
  for (int d = 0; d < 4; ++d)
    qf[d] = *reinterpret_cast<const short8*>(&qp[(size_t)(q0 + lq) * DHD + d * 16 + hi * 8]);

  f32x16 oacc[2];
#pragma unroll
  for (int e = 0; e < 16; ++e) { oacc[0][e] = 0.f; oacc[1][e] = 0.f; }
  float m2 = -INFINITY, lsum = 0.f;

  short8 ka[8], kb2[8];
  load_ktile(kp, 0, lane, ka);
  for (int it = 0; it < 32; it += 2) {
    const int kv0 = it << 6;
    load_ktile(kp, kv0 + 64, lane, kb2);                       // prefetch next
    attn_tile(ka, vp, mrow, has_mask, kv0, lane, hi, qf, oacc, m2, lsum);
    load_ktile(kp, (it == 30) ? 0 : kv0 + 128, lane, ka);      // prefetch next-next (wraps once, harmless)
    attn_tile(kb2, vp, mrow, has_mask, kv0 + 64, lane, hi, qf, oacc, m2, lsum);
  }

  // epilogue: lane holds q=q0+lq, d = db*32 + (e&3)+8*(e>>2)+4*hi -> 4 consecutive d per store
  const int b = bh >> 4, h = bh & 15;
  const float inv = 1.0f / lsum;
  u16* orow = O + ((size_t)(b * SEQ + q0 + lq) * NH + h) * DHD;
#pragma unroll
  for (int db = 0; db < 2; ++db)
#pragma unroll
    for (int g = 0; g < 4; ++g) {
      union { u16 u[4]; unsigned long long ll; } pk;
#pragma unroll
      for (int j = 0; j < 4; ++j) pk.u[j] = f2bf(oacc[db][g * 4 + j] * inv);
      *reinterpret_cast<unsigned long long*>(&orow[db * 32 + g * 8 + hi * 4]) = pk.ll;
    }
}

// ---- output projection: d_out = O @ Wo^T + bo (fp32 out)
__global__ __launch_bounds__(256) void out_proj_kernel(
    const u16* __restrict__ O, const float* __restrict__ Wo, const float* __restrict__ bo,
    float* __restrict__ out) {
  __shared__ u16 As[128 * 32];
  __shared__ u16 Bs[128 * 32];
  const int m0 = blockIdx.y * 128, n0 = blockIdx.x * 128;
  f32x4 acc[4][4];
  gemm_bt_body(O, Wo, m0, n0, As, Bs, acc);

  const int lane = threadIdx.x & 63;
  const int wr = (threadIdx.x >> 7) & 1, wc = (threadIdx.x >> 6) & 1;
  const int rbase = m0 + wr * 64 + ((lane >> 4) << 2);
  const int cbase = n0 + wc * 64 + (lane & 15);
#pragma unroll
  for (int n = 0; n < 4; ++n) {
    const int col = cbase + n * 16;
    const float bvv = bo[col];
#pragma unroll
    for (int m = 0; m < 4; ++m)
#pragma unroll
      for (int r = 0; r < 4; ++r) {
        const int row = rbase + m * 16 + r;
        out[(size_t)row * FD + col] = acc[m][n][r] + bvv;
      }
  }
}

extern "C" void kernel_launch(void* const* d_in, const int* in_sizes, int n_in,
                              void* d_out, int out_size, void* d_ws, size_t ws_size,
                              hipStream_t stream) {
  (void)in_sizes; (void)n_in; (void)out_size; (void)ws_size;
  const float* Q    = (const float*)d_in[0];
  const float* K    = (const float*)d_in[1];
  const float* V    = (const float*)d_in[2];
  const float* mask = (const float*)d_in[3];
  const float* Wq   = (const float*)d_in[4];
  const float* bq   = (const float*)d_in[5];
  const float* Wk   = (const float*)d_in[6];
  const float* bk   = (const float*)d_in[7];
  const float* Wv   = (const float*)d_in[8];
  const float* bv   = (const float*)d_in[9];
  const float* Wo   = (const float*)d_in[10];
  const float* bo   = (const float*)d_in[11];
  float* out = (float*)d_out;

  u16* ws = (u16*)d_ws;
  const size_t SZ = (size_t)4096 * 1024;   // B*S*F elements
  u16* qh = ws;            // [B,H,S,DH] bf16 (pre-scaled by 0.125*log2e)
  u16* kh = qh + SZ;       // K' fragment-major bf16
  u16* vF = kh + SZ;       // V' fragment-major bf16
  u16* O  = vF + SZ;       // [B,S,H,DH] bf16
  u32* mflag = (u32*)(O + SZ);

  hipMemsetAsync(mflag, 0, 4, stream);
  mask_check_kernel<<<dim3(2048), 256, 0, stream>>>((const u32*)mask, mflag);

  dim3 gproj(FD / 128, (2 * SEQ) / 128, 3);      // (8, 32, 3)
  proj_qkv_kernel<<<gproj, 256, 0, stream>>>(Q, K, V, Wq, Wk, Wv, bq, bk, bv, qh, kh, vF);

  attn_kernel<<<dim3(512), 256, 0, stream>>>(qh, kh, vF, mask, mflag, O);

  out_proj_kernel<<<dim3(FD / 128, (2 * SEQ) / 128), 256, 0, stream>>>(O, Wo, bo, out);
}

// Round 7
// 142.314 us; speedup vs baseline: 7.4524x; 1.1897x over previous
//
#include <hip/hip_runtime.h>
#include <hip/hip_bf16.h>

typedef unsigned short u16;
typedef unsigned int u32;
typedef __attribute__((ext_vector_type(4))) float f32x4;
typedef __attribute__((ext_vector_type(16))) float f32x16;
typedef __attribute__((ext_vector_type(8))) short short8;
typedef __attribute__((ext_vector_type(4))) u32 u32x4;

#define SEQ 2048
#define FD  1024
#define NH  16
#define DHD 64

__device__ __forceinline__ u16 f2bf(float f) {
  __hip_bfloat16 h = __float2bfloat16(f);
  return *reinterpret_cast<u16*>(&h);
}
__device__ __forceinline__ u32 pack2bf(float lo, float hi) {
  return (u32)f2bf(lo) | ((u32)f2bf(hi) << 16);
}

// async global->LDS, 16B per lane. LDS dest = wave-uniform base + lane*16.
#define GLOAD_LDS16(gp, lp)                                        \
  __builtin_amdgcn_global_load_lds(                                \
      (const __attribute__((address_space(1))) unsigned int*)(gp), \
      (__attribute__((address_space(3))) unsigned int*)(lp), 16, 0, 0)

// ---- prep: fp32->bf16 cast of Q,K,V (->Abf[3]) and Wq,Wk,Wv,Wo (->Wbf[4]);
// mask zero-check OR'd into flag. 8 f32/thread.
__global__ __launch_bounds__(256) void prep_kernel(
    const float* __restrict__ Q, const float* __restrict__ K, const float* __restrict__ V,
    const float* __restrict__ Wq, const float* __restrict__ Wk, const float* __restrict__ Wv,
    const float* __restrict__ Wo, const float* __restrict__ mask,
    u16* __restrict__ Abf, u16* __restrict__ Wbf, u32* __restrict__ flag) {
  const size_t i = ((size_t)blockIdx.x * 256 + threadIdx.x) * 8;
  if (i >= 16777216) {  // mask segment (4M f32)
    const u32* mp = (const u32*)mask + (i - 16777216);
    u32x4 a = *reinterpret_cast<const u32x4*>(mp);
    u32x4 b = *reinterpret_cast<const u32x4*>(mp + 4);
    u32 o = a[0] | a[1] | a[2] | a[3] | b[0] | b[1] | b[2] | b[3];
    if (__ballot(o != 0) != 0ull && (threadIdx.x & 63) == 0) atomicOr(flag, 1u);
    return;
  }
  const float* src;
  u16* dst;
  if (i < 12582912) {           // Q,K,V: 3 x 2^22
    const int s = (int)(i >> 22);
    const size_t off = i & 0x3FFFFF;
    src = (s == 0 ? Q : s == 1 ? K : V) + off;
    dst = Abf + i;
  } else {                      // W: 4 x 2^20
    const size_t j = i - 12582912;
    const int w = (int)(j >> 20);
    const size_t off = j & 0xFFFFF;
    src = (w == 0 ? Wq : w == 1 ? Wk : w == 2 ? Wv : Wo) + off;
    dst = Wbf + j;
  }
  f32x4 a = *reinterpret_cast<const f32x4*>(src);
  f32x4 b = *reinterpret_cast<const f32x4*>(src + 4);
  union { u32 u[4]; short8 s; } pk;
  pk.u[0] = pack2bf(a[0], a[1]); pk.u[1] = pack2bf(a[2], a[3]);
  pk.u[2] = pack2bf(b[0], b[1]); pk.u[3] = pack2bf(b[2], b[3]);
  *reinterpret_cast<short8*>(dst) = pk.s;
}

// ---- m97-structure 128x128 GEMM body: C = A[M,1024] * W[N,1024]^T, both bf16,
// BK=32, global_load_lds(16) staging, 16x16x32 MFMA, fp32 acc[4][4].
__device__ __forceinline__ void gemm128_bf16(const u16* __restrict__ A, const u16* __restrict__ W,
                                             int m0, int n0, u16* As, u16* Bs,
                                             f32x4 (&acc)[4][4]) {
  const int tid = threadIdx.x, lane = tid & 63, wv = tid >> 6;
  const int wr = (tid >> 7) & 1, wc = (tid >> 6) & 1;
  const int lr = lane & 15, lk = (lane >> 4) << 3;
  const int srow = lane >> 2;          // wave-local staging row (0..15)
  const int scol = (lane & 3) << 3;    // staging col (0,8,16,24)
#pragma unroll
  for (int m = 0; m < 4; ++m)
#pragma unroll
    for (int n = 0; n < 4; ++n) acc[m][n] = {0.f, 0.f, 0.f, 0.f};

  for (int k0 = 0; k0 < FD; k0 += 32) {
    __syncthreads();   // previous iteration's ds_reads done (lgkm drain)
#pragma unroll
    for (int c = 0; c < 2; ++c) {
      GLOAD_LDS16(&A[(size_t)(m0 + c * 64 + wv * 16 + srow) * FD + k0 + scol],
                  &As[(c * 64 + wv * 16) * 32]);
      GLOAD_LDS16(&W[(size_t)(n0 + c * 64 + wv * 16 + srow) * FD + k0 + scol],
                  &Bs[(c * 64 + wv * 16) * 32]);
    }
    __syncthreads();   // vmcnt(0) drain: staged tile visible
    short8 a[4], b[4];
#pragma unroll
    for (int m = 0; m < 4; ++m)
      a[m] = *reinterpret_cast<const short8*>(&As[(wr * 64 + m * 16 + lr) * 32 + lk]);
#pragma unroll
    for (int n = 0; n < 4; ++n)
      b[n] = *reinterpret_cast<const short8*>(&Bs[(wc * 64 + n * 16 + lr) * 32 + lk]);
#pragma unroll
    for (int m = 0; m < 4; ++m)
#pragma unroll
      for (int n = 0; n < 4; ++n)
        acc[m][n] = __builtin_amdgcn_mfma_f32_16x16x32_bf16(a[m], b[n], acc[m][n], 0, 0, 0);
  }
}

// ---- fused QKV projection (bf16 in). q -> [B,H,S,DH] (pre-scaled by 0.125*log2e);
// k,v -> fragment-major K'/V' (wave-contiguous 1KB attention loads).
// Block-id swizzle: y-grouped per XCD (A panels fetched once per XCD).
__global__ __launch_bounds__(256) void proj_qkv_kernel(
    const u16* __restrict__ Abf, const u16* __restrict__ Wbf,
    const float* __restrict__ bq, const float* __restrict__ bk, const float* __restrict__ bv,
    u16* __restrict__ qh, u16* __restrict__ kh, u16* __restrict__ vF) {
  __shared__ u16 As[128 * 32];
  __shared__ u16 Bs[128 * 32];
  const int bid = blockIdx.x;
  const int which = bid >> 8;
  const int rr = bid & 255;
  const int slot = rr >> 3;
  const int y = (rr & 7) + 8 * (slot & 3);  // XCD = rr%8 owns 4 m-bands, all n-tiles
  const int x = slot >> 2;
  const int m0 = y * 128, n0 = x * 128;
  const u16* A = Abf + ((size_t)which << 22);
  const u16* W = Wbf + ((size_t)which << 20);
  const float* bias = (which == 0) ? bq : (which == 1) ? bk : bv;
  const float qscale = 0.18033688011112042f;  // (1/8) * log2(e)

  f32x4 acc[4][4];
  gemm128_bf16(A, W, m0, n0, As, Bs, acc);

  u16* out = (which == 0) ? qh : (which == 1) ? kh : vF;
  const int lane = threadIdx.x & 63;
  const int wr = (threadIdx.x >> 7) & 1, wc = (threadIdx.x >> 6) & 1;
  const int rbase = m0 + wr * 64 + ((lane >> 4) << 2);
  const int cbase = n0 + wc * 64 + (lane & 15);
#pragma unroll
  for (int n = 0; n < 4; ++n) {
    const int col = cbase + n * 16;
    const float bvv = bias[col];
    const int h = col >> 6, dh = col & 63;
#pragma unroll
    for (int m = 0; m < 4; ++m) {
#pragma unroll
      for (int r = 0; r < 4; ++r) {
        const int row = rbase + m * 16 + r;
        const int b = row >> 11, s = row & 2047;
        float v = acc[m][n][r] + bvv;
        if (which == 0) v *= qscale;
        const size_t bhbase = (size_t)(b * 16 + h) * SEQ * DHD;
        size_t idx;
        if (which == 0) {
          idx = bhbase + (size_t)s * 64 + dh;                                   // [B,H,S,DH]
        } else if (which == 1) {
          idx = bhbase + ((size_t)(((s >> 5) * 4 + (dh >> 4)) * 64
                          + ((dh >> 3) & 1) * 32 + (s & 31)) << 3) + (dh & 7);  // K' frag
        } else {
          idx = bhbase + ((size_t)(((s >> 4) * 2 + (dh >> 5)) * 64
                          + ((s >> 3) & 1) * 32 + (dh & 31)) << 3) + (s & 7);   // V' frag
        }
        out[idx] = f2bf(v);
      }
    }
  }
}

__device__ __forceinline__ void load_ktile(const u16* __restrict__ kp, int kv0, int lane,
                                           short8 (&kf)[8]) {
#pragma unroll
  for (int h2 = 0; h2 < 2; ++h2)
#pragma unroll
    for (int d = 0; d < 4; ++d)
      kf[h2 * 4 + d] = *reinterpret_cast<const short8*>(
          &kp[((size_t)((((kv0 >> 5) + h2) * 4 + d) * 64 + lane)) << 3]);
}

// one 32q x 64kv tile: V loads issued first (hide under QK+softmax), K regs pre-loaded
__device__ __forceinline__ void attn_tile(
    const short8 (&kf)[8], const u16* __restrict__ vp, const float* __restrict__ mrow,
    u32 has_mask, int kv0, int lane, int hi, const short8 (&qf)[4],
    f32x16 (&oacc)[2], float& m2, float& lsum) {
  const float L2E = 1.44269504088896340736f;
  short8 vf[8];
#pragma unroll
  for (int kb = 0; kb < 4; ++kb)
#pragma unroll
    for (int db = 0; db < 2; ++db)
      vf[kb * 2 + db] = *reinterpret_cast<const short8*>(
          &vp[((size_t)((((kv0 >> 4) + kb) * 2 + db) * 64 + lane)) << 3]);

  f32x16 st[2];
#pragma unroll
  for (int h2 = 0; h2 < 2; ++h2) {
    f32x16 z;
#pragma unroll
    for (int e = 0; e < 16; ++e) z[e] = 0.f;
#pragma unroll
    for (int d = 0; d < 4; ++d)
      z = __builtin_amdgcn_mfma_f32_32x32x16_bf16(kf[h2 * 4 + d], qf[d], z, 0, 0, 0);
    st[h2] = z;
  }
  float p[32];
  if (__builtin_expect(has_mask != 0, 0)) {
#pragma unroll
    for (int h2 = 0; h2 < 2; ++h2)
#pragma unroll
      for (int g = 0; g < 4; ++g) {
        f32x4 mv = *reinterpret_cast<const f32x4*>(&mrow[kv0 + h2 * 32 + g * 8 + hi * 4]);
#pragma unroll
        for (int j = 0; j < 4; ++j)
          p[h2 * 16 + g * 4 + j] = fmaf(mv[j], L2E, st[h2][g * 4 + j]);
      }
  } else {
#pragma unroll
    for (int h2 = 0; h2 < 2; ++h2)
#pragma unroll
      for (int e = 0; e < 16; ++e) p[h2 * 16 + e] = st[h2][e];
  }
  float t8[8];
#pragma unroll
  for (int i = 0; i < 8; ++i)
    t8[i] = fmaxf(fmaxf(p[i], p[i + 8]), fmaxf(p[i + 16], p[i + 24]));
#pragma unroll
  for (int i = 0; i < 4; ++i) t8[i] = fmaxf(t8[i], t8[i + 4]);
  float mt = fmaxf(fmaxf(t8[0], t8[1]), fmaxf(t8[2], t8[3]));
  mt = fmaxf(mt, __shfl_xor(mt, 32));
  const float mnew = fmaxf(m2, mt);
  const float alpha = __builtin_amdgcn_exp2f(m2 - mnew);
  m2 = mnew;
#pragma unroll
  for (int i = 0; i < 32; ++i) p[i] = __builtin_amdgcn_exp2f(p[i] - m2);
  float s8[8];
#pragma unroll
  for (int i = 0; i < 8; ++i) s8[i] = (p[i] + p[i + 8]) + (p[i + 16] + p[i + 24]);
#pragma unroll
  for (int i = 0; i < 4; ++i) s8[i] += s8[i + 4];
  float ssum = (s8[0] + s8[1]) + (s8[2] + s8[3]);
  ssum += __shfl_xor(ssum, 32);
  lsum = lsum * alpha + ssum;
#pragma unroll
  for (int e = 0; e < 16; ++e) { oacc[0][e] *= alpha; oacc[1][e] *= alpha; }

#pragma unroll
  for (int kb = 0; kb < 4; ++kb) {
    const int pb = (kb >> 1) * 16 + (kb & 1) * 8;
    u32 x = pack2bf(p[pb + 0], p[pb + 1]);
    u32 y = pack2bf(p[pb + 4], p[pb + 5]);
    asm volatile("v_permlane32_swap_b32 %0, %1" : "+v"(x), "+v"(y));
    u32 zz = pack2bf(p[pb + 2], p[pb + 3]);
    u32 w = pack2bf(p[pb + 6], p[pb + 7]);
    asm volatile("v_permlane32_swap_b32 %0, %1" : "+v"(zz), "+v"(w));
    union { u32 u[4]; short8 s; } bf;
    bf.u[0] = x; bf.u[1] = zz; bf.u[2] = y; bf.u[3] = w;
#pragma unroll
    for (int db = 0; db < 2; ++db)
      oacc[db] = __builtin_amdgcn_mfma_f32_32x32x16_bf16(vf[kb * 2 + db], bf.s, oacc[db], 0, 0, 0);
  }
}

// ---- flash attention: 128 q-rows/block (4 waves x 32q, full-KV loop each),
// XCD-swizzled (each XCD owns 4 complete heads), K reg ping-pong prefetch. Zero LDS.
__global__ __launch_bounds__(256, 2) void attn_kernel(
    const u16* __restrict__ qh, const u16* __restrict__ kh, const u16* __restrict__ vF,
    const float* __restrict__ mask, const u32* __restrict__ mflag, u16* __restrict__ O) {
  const int wave = threadIdx.x >> 6, lane = threadIdx.x & 63;
  const int bid = blockIdx.x;
  const int vid = (bid & 7) * 64 + (bid >> 3);
  const int bh = vid >> 4;
  const int q0 = (vid & 15) * 128 + wave * 32;
  const int lq = lane & 31;
  const int hi = lane >> 5;
  const u16* qp = qh + (size_t)bh * SEQ * DHD;
  const u16* kp = kh + (size_t)bh * SEQ * DHD;
  const u16* vp = vF + (size_t)bh * SEQ * DHD;
  const float* mrow = mask + (size_t)(q0 + lq) * SEQ;
  const u32 has_mask = *mflag;

  short8 qf[4];
#pragma unroll
  for (int d = 0; d < 4; ++d)
    qf[d] = *reinterpret_cast<const short8*>(&qp[(size_t)(q0 + lq) * DHD + d * 16 + hi * 8]);

  f32x16 oacc[2];
#pragma unroll
  for (int e = 0; e < 16; ++e) { oacc[0][e] = 0.f; oacc[1][e] = 0.f; }
  float m2 = -INFINITY, lsum = 0.f;

  short8 ka[8], kb2[8];
  load_ktile(kp, 0, lane, ka);
  for (int it = 0; it < 32; it += 2) {
    const int kv0 = it << 6;
    load_ktile(kp, kv0 + 64, lane, kb2);
    attn_tile(ka, vp, mrow, has_mask, kv0, lane, hi, qf, oacc, m2, lsum);
    load_ktile(kp, (it == 30) ? 0 : kv0 + 128, lane, ka);
    attn_tile(kb2, vp, mrow, has_mask, kv0 + 64, lane, hi, qf, oacc, m2, lsum);
  }

  const int b = bh >> 4, h = bh & 15;
  const float inv = 1.0f / lsum;
  u16* orow = O + ((size_t)(b * SEQ + q0 + lq) * NH + h) * DHD;
#pragma unroll
  for (int db = 0; db < 2; ++db)
#pragma unroll
    for (int g = 0; g < 4; ++g) {
      union { u16 u[4]; unsigned long long ll; } pk;
#pragma unroll
      for (int j = 0; j < 4; ++j) pk.u[j] = f2bf(oacc[db][g * 4 + j] * inv);
      *reinterpret_cast<unsigned long long*>(&orow[db * 32 + g * 8 + hi * 4]) = pk.ll;
    }
}

// ---- output projection: d_out = O @ Wo^T + bo (fp32 out), m97 structure
__global__ __launch_bounds__(256) void out_proj_kernel(
    const u16* __restrict__ O, const u16* __restrict__ WoB, const float* __restrict__ bo,
    float* __restrict__ out) {
  __shared__ u16 As[128 * 32];
  __shared__ u16 Bs[128 * 32];
  const int rr = blockIdx.x;
  const int slot = rr >> 3;
  const int y = (rr & 7) + 8 * (slot & 3);
  const int x = slot >> 2;
  const int m0 = y * 128, n0 = x * 128;
  f32x4 acc[4][4];
  gemm128_bf16(O, WoB, m0, n0, As, Bs, acc);

  const int lane = threadIdx.x & 63;
  const int wr = (threadIdx.x >> 7) & 1, wc = (threadIdx.x >> 6) & 1;
  const int rbase = m0 + wr * 64 + ((lane >> 4) << 2);
  const int cbase = n0 + wc * 64 + (lane & 15);
#pragma unroll
  for (int n = 0; n < 4; ++n) {
    const int col = cbase + n * 16;
    const float bvv = bo[col];
#pragma unroll
    for (int m = 0; m < 4; ++m)
#pragma unroll
      for (int r = 0; r < 4; ++r) {
        const int row = rbase + m * 16 + r;
        out[(size_t)row * FD + col] = acc[m][n][r] + bvv;
      }
  }
}

extern "C" void kernel_launch(void* const* d_in, const int* in_sizes, int n_in,
                              void* d_out, int out_size, void* d_ws, size_t ws_size,
                              hipStream_t stream) {
  (void)in_sizes; (void)n_in; (void)out_size; (void)ws_size;
  const float* Q    = (const float*)d_in[0];
  const float* K    = (const float*)d_in[1];
  const float* V    = (const float*)d_in[2];
  const float* mask = (const float*)d_in[3];
  const float* Wq   = (const float*)d_in[4];
  const float* bq   = (const float*)d_in[5];
  const float* Wk   = (const float*)d_in[6];
  const float* bk   = (const float*)d_in[7];
  const float* Wv   = (const float*)d_in[8];
  const float* bv   = (const float*)d_in[9];
  const float* Wo   = (const float*)d_in[10];
  const float* bo   = (const float*)d_in[11];
  float* out = (float*)d_out;

  u16* ws = (u16*)d_ws;
  const size_t SZ = (size_t)4096 * 1024;   // B*S*F elements
  u16* qh  = ws;             // [B,H,S,DH] bf16 (q pre-scaled)
  u16* kh  = qh + SZ;        // K' fragment-major bf16
  u16* vF  = kh + SZ;        // V' fragment-major bf16
  u16* O   = vF + SZ;        // [B,S,H,DH] bf16
  u16* Abf = O + SZ;         // [3][4096][1024] bf16 (Q,K,V inputs cast)
  u16* Wbf = Abf + 3 * SZ;   // [4][1024][1024] bf16 (Wq,Wk,Wv,Wo cast)
  u32* mflag = (u32*)(Wbf + 4 * (size_t)1024 * 1024);

  hipMemsetAsync(mflag, 0, 4, stream);
  prep_kernel<<<dim3(10240), 256, 0, stream>>>(Q, K, V, Wq, Wk, Wv, Wo, mask, Abf, Wbf, mflag);

  proj_qkv_kernel<<<dim3(768), 256, 0, stream>>>(Abf, Wbf, bq, bk, bv, qh, kh, vF);

  attn_kernel<<<dim3(512), 256, 0, stream>>>(qh, kh, vF, mask, mflag, O);

  out_proj_kernel<<<dim3(256), 256, 0, stream>>>(O, Wbf + 3 * (size_t)1024 * 1024, bo, out);
}